// Round 1
// baseline (378.701 us; speedup 1.0000x reference)
//
#include <hip/hip_runtime.h>
#include <math.h>

#define B_ 2
#define DMODEL 128
#define DIN 256
#define DSTATE 16
#define DTR 8
#define OUTC 128
#define Lseq 4096
#define NC 64
#define LC 64

__device__ __forceinline__ float siluf(float x){ return x / (1.f + __expf(-x)); }

// ---------------- Kernel A: in_proj  x(b,L,128) @ W_in(128,512) -> xin(b,L,256), zs=silu(z) ----------------
__global__ __launch_bounds__(256) void k_inproj(const float* __restrict__ x1,
        const float* __restrict__ Win, float* __restrict__ xin, float* __restrict__ zs){
    __shared__ float xt[8*DMODEL];              // [c][p] layout: xt[c*8+p]
    int blk = blockIdx.x;
    int b = blk >> 9;                           // L/8 = 512 blocks per batch
    int l0 = (blk & 511) * 8;
    int t = threadIdx.x;
    const float* xb = x1 + (size_t)b * DMODEL * Lseq;
    #pragma unroll
    for (int i = 0; i < 4; ++i){
        int e = t + i*256;
        int c = e >> 3, p = e & 7;
        xt[e] = xb[(size_t)c*Lseq + l0 + p];    // xt[c*8+p] = e  (conflict-free)
    }
    __syncthreads();
    float acc0[8], acc1[8];
    #pragma unroll
    for (int p=0;p<8;++p){acc0[p]=0.f;acc1[p]=0.f;}
    for (int k=0;k<DMODEL;++k){
        float w0 = Win[k*512 + t];
        float w1 = Win[k*512 + t + 256];
        #pragma unroll
        for (int p=0;p<8;++p){
            float xv = xt[k*8 + p];             // broadcast
            acc0[p] = fmaf(xv, w0, acc0[p]);
            acc1[p] = fmaf(xv, w1, acc1[p]);
        }
    }
    #pragma unroll
    for (int p=0;p<8;++p){
        size_t base = ((size_t)(b*Lseq + l0 + p))*DIN;
        xin[base + t] = acc0[p];
        zs[base + t]  = siluf(acc1[p]);
    }
}

// ---------------- Kernel B: causal depthwise conv + silu -> xc; x_proj -> (dtraw,B,C); dt_proj+softplus ----
__global__ __launch_bounds__(256) void k_conv_proj(const float* __restrict__ xin,
        const float* __restrict__ convw, const float* __restrict__ convb,
        const float* __restrict__ Wx, const float* __restrict__ Wdt,
        const float* __restrict__ bdt,
        float* __restrict__ xc, float* __restrict__ dt,
        float* __restrict__ Bm, float* __restrict__ Cm){
    __shared__ float xcs[DIN];
    __shared__ float xdbl[40];
    int blk = blockIdx.x;
    int b = blk >> 12;
    int l = blk & 4095;
    int t = threadIdx.x;
    float acc = convb[t];
    #pragma unroll
    for (int k=0;k<4;++k){
        int lp = l - 3 + k;
        if (lp >= 0) acc = fmaf(xin[((size_t)(b*Lseq+lp))*DIN + t], convw[t*4+k], acc);
    }
    float xcv = siluf(acc);
    xcs[t] = xcv;
    xc[((size_t)(b*Lseq+l))*DIN + t] = xcv;
    __syncthreads();
    // x_proj: 40 outputs, one wave computes 10
    int w = t >> 6, lane = t & 63;
    for (int jj=0;jj<10;++jj){
        int j = w*10 + jj;
        float p = 0.f;
        #pragma unroll
        for (int i=0;i<4;++i){
            int d = lane + i*64;
            p = fmaf(xcs[d], Wx[d*40 + j], p);
        }
        #pragma unroll
        for (int m=32;m>0;m>>=1) p += __shfl_xor(p, m, 64);
        if (lane == 0) xdbl[j] = p;
    }
    __syncthreads();
    float a2 = bdt[t];
    #pragma unroll
    for (int r=0;r<DTR;++r) a2 = fmaf(xdbl[r], Wdt[r*DIN + t], a2);
    float dtv = (a2 > 20.f) ? a2 : log1pf(__expf(a2));
    dt[((size_t)(b*Lseq+l))*DIN + t] = dtv;
    if (t < DSTATE)            Bm[((size_t)(b*Lseq+l))*DSTATE + t]            = xdbl[DTR + t];
    else if (t < 2*DSTATE)     Cm[((size_t)(b*Lseq+l))*DSTATE + (t-DSTATE)]   = xdbl[DTR + DSTATE + (t-DSTATE)];
}

// ---------------- Kernel C: chunked scan pass 1: per-chunk product P and zero-init partial state S --------
__global__ __launch_bounds__(256) void k_scan1(const float* __restrict__ dt,
        const float* __restrict__ xc, const float* __restrict__ Bm,
        const float* __restrict__ Alog,
        float* __restrict__ Pw, float* __restrict__ Sw){
    __shared__ float dts[LC*16], xcs[LC*16], Bs[LC*16];
    int blk = blockIdx.x;
    int b = blk >> 10;
    int rem = blk & 1023;
    int c = rem >> 4;
    int d0 = (rem & 15) << 4;
    int l0 = c * LC;
    int t = threadIdx.x;
    #pragma unroll
    for (int i=0;i<4;++i){
        int e = t + i*256;
        int l = e >> 4, dd = e & 15;
        size_t g = ((size_t)(b*Lseq + l0 + l))*DIN + d0 + dd;
        dts[e] = dt[g];
        xcs[e] = xc[g];
        Bs[e]  = Bm[((size_t)(b*Lseq + l0 + l))*DSTATE + dd];
    }
    __syncthreads();
    int dg = t >> 4, s = t & 15;
    float Av = -__expf(Alog[(d0+dg)*DSTATE + s]);
    float P = 1.f, S = 0.f;
    for (int l=0;l<LC;++l){
        float dtv = dts[l*16+dg];
        float xcv = xcs[l*16+dg];
        float bv  = Bs[l*16+s];
        float dA  = __expf(dtv * Av);
        S = fmaf(dA, S, dtv * bv * xcv);
        P *= dA;
    }
    size_t idx = (((size_t)(b*NC + c))*DIN + d0 + dg)*DSTATE + s;
    Pw[idx] = P; Sw[idx] = S;
}

// ---------------- Kernel D: pass 2, sequential combine over 64 chunks (8192 independent channels) ---------
__global__ __launch_bounds__(256) void k_scan2(const float* __restrict__ Pw,
        const float* __restrict__ Sw, float* __restrict__ Iw){
    int g = blockIdx.x*256 + threadIdx.x;  // 8192
    int b = g >> 12;
    int r = g & 4095;
    float H = 0.f;
    for (int c=0;c<NC;++c){
        size_t idx = ((size_t)(b*NC + c))*4096 + r;
        Iw[idx] = H;                       // state entering chunk c
        H = fmaf(Pw[idx], H, Sw[idx]);
    }
}

// ---------------- Kernel E: pass 3: replay with correct init; y = h·C, + xc*D, * silu(z) -------------------
__global__ __launch_bounds__(256) void k_scan3(const float* __restrict__ dt,
        const float* __restrict__ xc, const float* __restrict__ Bm,
        const float* __restrict__ Cm, const float* __restrict__ Alog,
        const float* __restrict__ Dv, const float* __restrict__ zs,
        const float* __restrict__ Iw, float* __restrict__ yg){
    __shared__ float dts[LC*16], xcs[LC*16], Bs[LC*16], Cs[LC*16], ys[LC*16];
    int blk = blockIdx.x;
    int b = blk >> 10;
    int rem = blk & 1023;
    int c = rem >> 4;
    int d0 = (rem & 15) << 4;
    int l0 = c * LC;
    int t = threadIdx.x;
    #pragma unroll
    for (int i=0;i<4;++i){
        int e = t + i*256;
        int l = e >> 4, dd = e & 15;
        size_t g = ((size_t)(b*Lseq + l0 + l))*DIN + d0 + dd;
        size_t gs = ((size_t)(b*Lseq + l0 + l))*DSTATE + dd;
        dts[e] = dt[g];
        xcs[e] = xc[g];
        Bs[e]  = Bm[gs];
        Cs[e]  = Cm[gs];
    }
    __syncthreads();
    int dg = t >> 4, s = t & 15;
    float Av = -__expf(Alog[(d0+dg)*DSTATE + s]);
    float h = Iw[(((size_t)(b*NC + c))*DIN + d0 + dg)*DSTATE + s];
    for (int l=0;l<LC;++l){
        float dtv = dts[l*16+dg];
        float xcv = xcs[l*16+dg];
        float bv  = Bs[l*16+s];
        float dA  = __expf(dtv * Av);
        h = fmaf(dA, h, dtv * bv * xcv);
        float p = h * Cs[l*16+s];
        p += __shfl_xor(p, 1, 64);
        p += __shfl_xor(p, 2, 64);
        p += __shfl_xor(p, 4, 64);
        p += __shfl_xor(p, 8, 64);
        if (s == 0) ys[l*16+dg] = p;
    }
    __syncthreads();
    #pragma unroll
    for (int i=0;i<4;++i){
        int e = t + i*256;
        int l = e >> 4, dd = e & 15;
        size_t g = ((size_t)(b*Lseq + l0 + l))*DIN + d0 + dd;
        yg[g] = (ys[e] + Dv[d0+dd]*xcs[e]) * zs[g];
    }
}

// ---------------- Kernel F: out_proj (256->128) + LayerNorm + NCHW transpose store ------------------------
__global__ __launch_bounds__(128) void k_out(const float* __restrict__ yg,
        const float* __restrict__ Wout, const float* __restrict__ lng,
        const float* __restrict__ lnb, float* __restrict__ out){
    __shared__ float ysm[DIN];
    __shared__ float red[2];
    int blk = blockIdx.x;
    int b = blk >> 12, l = blk & 4095;
    int t = threadIdx.x;
    size_t base = ((size_t)(b*Lseq + l))*DIN;
    ysm[t]       = yg[base + t];
    ysm[t + 128] = yg[base + t + 128];
    __syncthreads();
    float acc = 0.f;
    for (int k=0;k<DIN;++k) acc = fmaf(ysm[k], Wout[k*OUTC + t], acc);
    int w = t >> 6, lane = t & 63;
    float sum = acc;
    #pragma unroll
    for (int m=32;m>0;m>>=1) sum += __shfl_xor(sum, m, 64);
    if (lane == 0) red[w] = sum;
    __syncthreads();
    float mu = (red[0] + red[1]) * (1.f/128.f);
    float dv = acc - mu;
    float sq = dv*dv;
    #pragma unroll
    for (int m=32;m>0;m>>=1) sq += __shfl_xor(sq, m, 64);
    __syncthreads();
    if (lane == 0) red[w] = sq;
    __syncthreads();
    float var = (red[0] + red[1]) * (1.f/128.f);
    float o = dv * rsqrtf(var + 1e-5f) * lng[t] + lnb[t];
    out[((size_t)(b*OUTC + t))*Lseq + l] = o;
}

extern "C" void kernel_launch(void* const* d_in, const int* in_sizes, int n_in,
                              void* d_out, int out_size, void* d_ws, size_t ws_size,
                              hipStream_t stream) {
    const float* x1    = (const float*)d_in[0];
    const float* Win   = (const float*)d_in[1];
    const float* convw = (const float*)d_in[2];
    const float* convb = (const float*)d_in[3];
    const float* Wx    = (const float*)d_in[4];
    const float* Wdt   = (const float*)d_in[5];
    const float* bdt   = (const float*)d_in[6];
    const float* Alog  = (const float*)d_in[7];
    const float* Dv    = (const float*)d_in[8];
    const float* Wout  = (const float*)d_in[9];
    const float* lng   = (const float*)d_in[10];
    const float* lnb   = (const float*)d_in[11];
    float* out = (float*)d_out;

    float* ws  = (float*)d_ws;
    float* xin = ws;                  // 2,097,152
    float* zs  = xin + 2097152;       // 2,097,152
    float* xc  = zs  + 2097152;       // 2,097,152
    float* dt  = xc  + 2097152;       // 2,097,152
    float* Bm  = dt  + 2097152;       //   131,072
    float* Cm  = Bm  + 131072;        //   131,072
    float* yg  = Cm  + 131072;        // 2,097,152
    float* Pw  = yg  + 2097152;       //   524,288
    float* Sw  = Pw  + 524288;        //   524,288
    float* Iw  = Sw  + 524288;        //   524,288  (total ~49.3 MB)

    k_inproj   <<<1024, 256, 0, stream>>>(x1, Win, xin, zs);
    k_conv_proj<<<8192, 256, 0, stream>>>(xin, convw, convb, Wx, Wdt, bdt, xc, dt, Bm, Cm);
    k_scan1    <<<2048, 256, 0, stream>>>(dt, xc, Bm, Alog, Pw, Sw);
    k_scan2    <<<32,   256, 0, stream>>>(Pw, Sw, Iw);
    k_scan3    <<<2048, 256, 0, stream>>>(dt, xc, Bm, Cm, Alog, Dv, zs, Iw, yg);
    k_out      <<<8192, 128, 0, stream>>>(yg, Wout, lng, lnb, out);
}

// Round 2
// 229.594 us; speedup vs baseline: 1.6494x; 1.6494x over previous
//
#include <hip/hip_runtime.h>
#include <math.h>

#define B_ 2
#define DMODEL 128
#define DIN 256
#define DSTATE 16
#define DTR 8
#define OUTC 128
#define Lseq 4096
#define NC 64
#define LC 64

__device__ __forceinline__ float siluf(float x){ return x / (1.f + __expf(-x)); }

// ---------------- Kernel A: in_proj  x(b,L,128) @ W_in(128,512) -> xin(b,L,256), zs=silu(z) ----------------
__global__ __launch_bounds__(256) void k_inproj(const float* __restrict__ x1,
        const float* __restrict__ Win, float* __restrict__ xin, float* __restrict__ zs){
    __shared__ float xt[8*DMODEL];              // [c][p] layout: xt[c*8+p]
    int blk = blockIdx.x;
    int b = blk >> 9;                           // L/8 = 512 blocks per batch
    int l0 = (blk & 511) * 8;
    int t = threadIdx.x;
    const float* xb = x1 + (size_t)b * DMODEL * Lseq;
    #pragma unroll
    for (int i = 0; i < 4; ++i){
        int e = t + i*256;
        int c = e >> 3, p = e & 7;
        xt[e] = xb[(size_t)c*Lseq + l0 + p];    // xt[c*8+p] = e  (conflict-free)
    }
    __syncthreads();
    float acc0[8], acc1[8];
    #pragma unroll
    for (int p=0;p<8;++p){acc0[p]=0.f;acc1[p]=0.f;}
    for (int k=0;k<DMODEL;++k){
        float w0 = Win[k*512 + t];
        float w1 = Win[k*512 + t + 256];
        #pragma unroll
        for (int p=0;p<8;++p){
            float xv = xt[k*8 + p];             // broadcast
            acc0[p] = fmaf(xv, w0, acc0[p]);
            acc1[p] = fmaf(xv, w1, acc1[p]);
        }
    }
    #pragma unroll
    for (int p=0;p<8;++p){
        size_t base = ((size_t)(b*Lseq + l0 + p))*DIN;
        xin[base + t] = acc0[p];
        zs[base + t]  = siluf(acc1[p]);
    }
}

// ---------------- Kernel B (rewritten): 32 timesteps per block; conv+silu, x_proj GEMM-style, dt_proj ------
// 256 blocks (b=2 x 128 chunks of 32 l). 256 threads.
//  Phase 1 (conv): thread = channel d; sliding 4-tap window in registers over 32 rows.
//  Phase 2 (x_proj): threads = 32 l-groups x 8 j-groups; 5 j per thread; acc over d with LDS broadcast.
//  Phase 3 (dt_proj): thread = channel d; Wdt row in registers; loop 32 l.
__global__ __launch_bounds__(256) void k_conv_proj(const float* __restrict__ xin,
        const float* __restrict__ convw, const float* __restrict__ convb,
        const float* __restrict__ Wx, const float* __restrict__ Wdt,
        const float* __restrict__ bdt,
        float* __restrict__ xc, float* __restrict__ dt,
        float* __restrict__ Bm, float* __restrict__ Cm){
    __shared__ float xcs[32*257];   // [l][d], stride 257 to break bank aliasing
    __shared__ float xdbl[32*40];   // [l][j]
    int blk = blockIdx.x;           // 256 blocks
    int b  = blk >> 7;
    int l0 = (blk & 127) << 5;
    int t  = threadIdx.x;

    // ---- phase 1: causal depthwise conv + silu ----
    float w0 = convw[t*4+0], w1 = convw[t*4+1], w2 = convw[t*4+2], w3 = convw[t*4+3];
    float bb = convb[t];
    const float* xinb = xin + ((size_t)(b*Lseq + l0))*DIN + t;
    float x3, x2, x1;               // x[l-3], x[l-2], x[l-1]
    if (l0 == 0) { x3 = x2 = x1 = 0.f; }
    else { x3 = xinb[-3*DIN]; x2 = xinb[-2*DIN]; x1 = xinb[-1*DIN]; }
    float* xcg = xc + ((size_t)(b*Lseq + l0))*DIN + t;
    #pragma unroll 4
    for (int l = 0; l < 32; ++l){
        float x0 = xinb[l*DIN];
        float acc = bb;
        acc = fmaf(x3, w0, acc);
        acc = fmaf(x2, w1, acc);
        acc = fmaf(x1, w2, acc);
        acc = fmaf(x0, w3, acc);
        float v = siluf(acc);
        xcs[l*257 + t] = v;
        xcg[l*DIN] = v;
        x3 = x2; x2 = x1; x1 = x0;
    }
    __syncthreads();

    // ---- phase 2: x_proj  xdbl[l][j] = sum_d xcs[l][d] * Wx[d][j] ----
    {
        int jg = t & 7;             // 8 j-groups x 5 j
        int lg = t >> 3;            // 32 l
        int j0 = jg * 5;
        float a0=0.f, a1=0.f, a2=0.f, a3=0.f, a4=0.f;
        const float* xrow = xcs + lg*257;
        const float* wbase = Wx + j0;
        #pragma unroll 8
        for (int d = 0; d < 256; ++d){
            float xv = xrow[d];             // LDS broadcast across j-groups
            const float* wr = wbase + d*40; // 160B span per instr, L1-resident
            a0 = fmaf(xv, wr[0], a0);
            a1 = fmaf(xv, wr[1], a1);
            a2 = fmaf(xv, wr[2], a2);
            a3 = fmaf(xv, wr[3], a3);
            a4 = fmaf(xv, wr[4], a4);
        }
        float* xo = xdbl + lg*40 + j0;
        xo[0]=a0; xo[1]=a1; xo[2]=a2; xo[3]=a3; xo[4]=a4;
    }
    __syncthreads();

    // ---- phase 3: dt_proj + softplus; B/C extraction ----
    {
        float wd[DTR];
        #pragma unroll
        for (int r=0;r<DTR;++r) wd[r] = Wdt[r*DIN + t];
        float bv = bdt[t];
        float* dtg = dt + ((size_t)(b*Lseq + l0))*DIN + t;
        #pragma unroll 4
        for (int l=0;l<32;++l){
            float a = bv;
            #pragma unroll
            for (int r=0;r<DTR;++r) a = fmaf(xdbl[l*40 + r], wd[r], a);
            float dtv = (a > 20.f) ? a : log1pf(__expf(a));
            dtg[l*DIN] = dtv;
        }
    }
    // B/C: 32 l x 32 vals
    for (int o = t; o < 1024; o += 256){
        int l = o >> 5, q = o & 31;
        float v = xdbl[l*40 + DTR + q];
        size_t g = ((size_t)(b*Lseq + l0 + l))*DSTATE;
        if (q < DSTATE) Bm[g + q] = v;
        else            Cm[g + (q - DSTATE)] = v;
    }
}

// ---------------- Kernel C: chunked scan pass 1: per-chunk product P and zero-init partial state S --------
__global__ __launch_bounds__(256) void k_scan1(const float* __restrict__ dt,
        const float* __restrict__ xc, const float* __restrict__ Bm,
        const float* __restrict__ Alog,
        float* __restrict__ Pw, float* __restrict__ Sw){
    __shared__ float dts[LC*16], xcs[LC*16], Bs[LC*16];
    int blk = blockIdx.x;
    int b = blk >> 10;
    int rem = blk & 1023;
    int c = rem >> 4;
    int d0 = (rem & 15) << 4;
    int l0 = c * LC;
    int t = threadIdx.x;
    #pragma unroll
    for (int i=0;i<4;++i){
        int e = t + i*256;
        int l = e >> 4, dd = e & 15;
        size_t g = ((size_t)(b*Lseq + l0 + l))*DIN + d0 + dd;
        dts[e] = dt[g];
        xcs[e] = xc[g];
        Bs[e]  = Bm[((size_t)(b*Lseq + l0 + l))*DSTATE + dd];
    }
    __syncthreads();
    int dg = t >> 4, s = t & 15;
    float Av = -__expf(Alog[(d0+dg)*DSTATE + s]);
    float P = 1.f, S = 0.f;
    for (int l=0;l<LC;++l){
        float dtv = dts[l*16+dg];
        float xcv = xcs[l*16+dg];
        float bv  = Bs[l*16+s];
        float dA  = __expf(dtv * Av);
        S = fmaf(dA, S, dtv * bv * xcv);
        P *= dA;
    }
    size_t idx = (((size_t)(b*NC + c))*DIN + d0 + dg)*DSTATE + s;
    Pw[idx] = P; Sw[idx] = S;
}

// ---------------- Kernel D: pass 2, sequential combine over 64 chunks (8192 independent channels) ---------
__global__ __launch_bounds__(256) void k_scan2(const float* __restrict__ Pw,
        const float* __restrict__ Sw, float* __restrict__ Iw){
    int g = blockIdx.x*256 + threadIdx.x;  // 8192
    int b = g >> 12;
    int r = g & 4095;
    float H = 0.f;
    for (int c=0;c<NC;++c){
        size_t idx = ((size_t)(b*NC + c))*4096 + r;
        Iw[idx] = H;                       // state entering chunk c
        H = fmaf(Pw[idx], H, Sw[idx]);
    }
}

// ---------------- Kernel E: pass 3: replay with correct init; y = h·C, + xc*D, * silu(z) -------------------
__global__ __launch_bounds__(256) void k_scan3(const float* __restrict__ dt,
        const float* __restrict__ xc, const float* __restrict__ Bm,
        const float* __restrict__ Cm, const float* __restrict__ Alog,
        const float* __restrict__ Dv, const float* __restrict__ zs,
        const float* __restrict__ Iw, float* __restrict__ yg){
    __shared__ float dts[LC*16], xcs[LC*16], Bs[LC*16], Cs[LC*16], ys[LC*16];
    int blk = blockIdx.x;
    int b = blk >> 10;
    int rem = blk & 1023;
    int c = rem >> 4;
    int d0 = (rem & 15) << 4;
    int l0 = c * LC;
    int t = threadIdx.x;
    #pragma unroll
    for (int i=0;i<4;++i){
        int e = t + i*256;
        int l = e >> 4, dd = e & 15;
        size_t g = ((size_t)(b*Lseq + l0 + l))*DIN + d0 + dd;
        size_t gs = ((size_t)(b*Lseq + l0 + l))*DSTATE + dd;
        dts[e] = dt[g];
        xcs[e] = xc[g];
        Bs[e]  = Bm[gs];
        Cs[e]  = Cm[gs];
    }
    __syncthreads();
    int dg = t >> 4, s = t & 15;
    float Av = -__expf(Alog[(d0+dg)*DSTATE + s]);
    float h = Iw[(((size_t)(b*NC + c))*DIN + d0 + dg)*DSTATE + s];
    for (int l=0;l<LC;++l){
        float dtv = dts[l*16+dg];
        float xcv = xcs[l*16+dg];
        float bv  = Bs[l*16+s];
        float dA  = __expf(dtv * Av);
        h = fmaf(dA, h, dtv * bv * xcv);
        float p = h * Cs[l*16+s];
        p += __shfl_xor(p, 1, 64);
        p += __shfl_xor(p, 2, 64);
        p += __shfl_xor(p, 4, 64);
        p += __shfl_xor(p, 8, 64);
        if (s == 0) ys[l*16+dg] = p;
    }
    __syncthreads();
    #pragma unroll
    for (int i=0;i<4;++i){
        int e = t + i*256;
        int l = e >> 4, dd = e & 15;
        size_t g = ((size_t)(b*Lseq + l0 + l))*DIN + d0 + dd;
        yg[g] = (ys[e] + Dv[d0+dd]*xcs[e]) * zs[g];
    }
}

// ---------------- Kernel F: out_proj (256->128) + LayerNorm + NCHW transpose store ------------------------
__global__ __launch_bounds__(128) void k_out(const float* __restrict__ yg,
        const float* __restrict__ Wout, const float* __restrict__ lng,
        const float* __restrict__ lnb, float* __restrict__ out){
    __shared__ float ysm[DIN];
    __shared__ float red[2];
    int blk = blockIdx.x;
    int b = blk >> 12, l = blk & 4095;
    int t = threadIdx.x;
    size_t base = ((size_t)(b*Lseq + l))*DIN;
    ysm[t]       = yg[base + t];
    ysm[t + 128] = yg[base + t + 128];
    __syncthreads();
    float acc = 0.f;
    for (int k=0;k<DIN;++k) acc = fmaf(ysm[k], Wout[k*OUTC + t], acc);
    int w = t >> 6, lane = t & 63;
    float sum = acc;
    #pragma unroll
    for (int m=32;m>0;m>>=1) sum += __shfl_xor(sum, m, 64);
    if (lane == 0) red[w] = sum;
    __syncthreads();
    float mu = (red[0] + red[1]) * (1.f/128.f);
    float dv = acc - mu;
    float sq = dv*dv;
    #pragma unroll
    for (int m=32;m>0;m>>=1) sq += __shfl_xor(sq, m, 64);
    __syncthreads();
    if (lane == 0) red[w] = sq;
    __syncthreads();
    float var = (red[0] + red[1]) * (1.f/128.f);
    float o = dv * rsqrtf(var + 1e-5f) * lng[t] + lnb[t];
    out[((size_t)(b*OUTC + t))*Lseq + l] = o;
}

extern "C" void kernel_launch(void* const* d_in, const int* in_sizes, int n_in,
                              void* d_out, int out_size, void* d_ws, size_t ws_size,
                              hipStream_t stream) {
    const float* x1    = (const float*)d_in[0];
    const float* Win   = (const float*)d_in[1];
    const float* convw = (const float*)d_in[2];
    const float* convb = (const float*)d_in[3];
    const float* Wx    = (const float*)d_in[4];
    const float* Wdt   = (const float*)d_in[5];
    const float* bdt   = (const float*)d_in[6];
    const float* Alog  = (const float*)d_in[7];
    const float* Dv    = (const float*)d_in[8];
    const float* Wout  = (const float*)d_in[9];
    const float* lng   = (const float*)d_in[10];
    const float* lnb   = (const float*)d_in[11];
    float* out = (float*)d_out;

    float* ws  = (float*)d_ws;
    float* xin = ws;                  // 2,097,152
    float* zs  = xin + 2097152;       // 2,097,152
    float* xc  = zs  + 2097152;       // 2,097,152
    float* dt  = xc  + 2097152;       // 2,097,152
    float* Bm  = dt  + 2097152;       //   131,072
    float* Cm  = Bm  + 131072;        //   131,072
    float* yg  = Cm  + 131072;        // 2,097,152
    float* Pw  = yg  + 2097152;       //   524,288
    float* Sw  = Pw  + 524288;        //   524,288
    float* Iw  = Sw  + 524288;        //   524,288  (total ~49.3 MB)

    k_inproj   <<<1024, 256, 0, stream>>>(x1, Win, xin, zs);
    k_conv_proj<<<256,  256, 0, stream>>>(xin, convw, convb, Wx, Wdt, bdt, xc, dt, Bm, Cm);
    k_scan1    <<<2048, 256, 0, stream>>>(dt, xc, Bm, Alog, Pw, Sw);
    k_scan2    <<<32,   256, 0, stream>>>(Pw, Sw, Iw);
    k_scan3    <<<2048, 256, 0, stream>>>(dt, xc, Bm, Cm, Alog, Dv, zs, Iw, yg);
    k_out      <<<8192, 128, 0, stream>>>(yg, Wout, lng, lnb, out);
}

// Round 3
// 209.885 us; speedup vs baseline: 1.8043x; 1.0939x over previous
//
#include <hip/hip_runtime.h>
#include <math.h>

#define B_ 2
#define DMODEL 128
#define DIN 256
#define DSTATE 16
#define DTR 8
#define OUTC 128
#define Lseq 4096
#define NC 128
#define LC 32

__device__ __forceinline__ float siluf(float x){ return x / (1.f + __expf(-x)); }

// ---------------- Kernel A: in_proj  x(b,L,128) @ W_in(128,512) -> xin(b,L,256), zs=silu(z) ----------------
__global__ __launch_bounds__(256) void k_inproj(const float* __restrict__ x1,
        const float* __restrict__ Win, float* __restrict__ xin, float* __restrict__ zs){
    __shared__ float xt[8*DMODEL];              // [c][p] layout: xt[c*8+p]
    int blk = blockIdx.x;
    int b = blk >> 9;                           // L/8 = 512 blocks per batch
    int l0 = (blk & 511) * 8;
    int t = threadIdx.x;
    const float* xb = x1 + (size_t)b * DMODEL * Lseq;
    #pragma unroll
    for (int i = 0; i < 4; ++i){
        int e = t + i*256;
        int c = e >> 3, p = e & 7;
        xt[e] = xb[(size_t)c*Lseq + l0 + p];
    }
    __syncthreads();
    float acc0[8], acc1[8];
    #pragma unroll
    for (int p=0;p<8;++p){acc0[p]=0.f;acc1[p]=0.f;}
    for (int k=0;k<DMODEL;++k){
        float w0 = Win[k*512 + t];
        float w1 = Win[k*512 + t + 256];
        #pragma unroll
        for (int p=0;p<8;++p){
            float xv = xt[k*8 + p];
            acc0[p] = fmaf(xv, w0, acc0[p]);
            acc1[p] = fmaf(xv, w1, acc1[p]);
        }
    }
    #pragma unroll
    for (int p=0;p<8;++p){
        size_t base = ((size_t)(b*Lseq + l0 + p))*DIN;
        xin[base + t] = acc0[p];
        zs[base + t]  = siluf(acc1[p]);
    }
}

// ---------------- k_prep: Avw[s][d] = -exp(A_log[d][s])  (coalesced layout for the scan kernels) ----------
__global__ __launch_bounds__(256) void k_prep(const float* __restrict__ Alog, float* __restrict__ Avw){
    int e = blockIdx.x*256 + threadIdx.x;      // 4096
    int s = e >> 8, d = e & 255;
    Avw[e] = -__expf(Alog[d*DSTATE + s]);
}

// ---------------- Kernel B: 32 timesteps per block; conv+silu, x_proj GEMM-style, dt_proj ------------------
__global__ __launch_bounds__(256) void k_conv_proj(const float* __restrict__ xin,
        const float* __restrict__ convw, const float* __restrict__ convb,
        const float* __restrict__ Wx, const float* __restrict__ Wdt,
        const float* __restrict__ bdt,
        float* __restrict__ xc, float* __restrict__ dt,
        float* __restrict__ Bm, float* __restrict__ Cm){
    __shared__ float xcs[32*257];
    __shared__ float xdbl[32*40];
    int blk = blockIdx.x;
    int b  = blk >> 7;
    int l0 = (blk & 127) << 5;
    int t  = threadIdx.x;

    float w0 = convw[t*4+0], w1 = convw[t*4+1], w2 = convw[t*4+2], w3 = convw[t*4+3];
    float bb = convb[t];
    const float* xinb = xin + ((size_t)(b*Lseq + l0))*DIN + t;
    float x3, x2, x1;
    if (l0 == 0) { x3 = x2 = x1 = 0.f; }
    else { x3 = xinb[-3*DIN]; x2 = xinb[-2*DIN]; x1 = xinb[-1*DIN]; }
    float* xcg = xc + ((size_t)(b*Lseq + l0))*DIN + t;
    #pragma unroll 4
    for (int l = 0; l < 32; ++l){
        float x0 = xinb[l*DIN];
        float acc = bb;
        acc = fmaf(x3, w0, acc);
        acc = fmaf(x2, w1, acc);
        acc = fmaf(x1, w2, acc);
        acc = fmaf(x0, w3, acc);
        float v = siluf(acc);
        xcs[l*257 + t] = v;
        xcg[l*DIN] = v;
        x3 = x2; x2 = x1; x1 = x0;
    }
    __syncthreads();

    {
        int jg = t & 7;
        int lg = t >> 3;
        int j0 = jg * 5;
        float a0=0.f, a1=0.f, a2=0.f, a3=0.f, a4=0.f;
        const float* xrow = xcs + lg*257;
        const float* wbase = Wx + j0;
        #pragma unroll 8
        for (int d = 0; d < 256; ++d){
            float xv = xrow[d];
            const float* wr = wbase + d*40;
            a0 = fmaf(xv, wr[0], a0);
            a1 = fmaf(xv, wr[1], a1);
            a2 = fmaf(xv, wr[2], a2);
            a3 = fmaf(xv, wr[3], a3);
            a4 = fmaf(xv, wr[4], a4);
        }
        float* xo = xdbl + lg*40 + j0;
        xo[0]=a0; xo[1]=a1; xo[2]=a2; xo[3]=a3; xo[4]=a4;
    }
    __syncthreads();

    {
        float wd[DTR];
        #pragma unroll
        for (int r=0;r<DTR;++r) wd[r] = Wdt[r*DIN + t];
        float bv = bdt[t];
        float* dtg = dt + ((size_t)(b*Lseq + l0))*DIN + t;
        #pragma unroll 4
        for (int l=0;l<32;++l){
            float a = bv;
            #pragma unroll
            for (int r=0;r<DTR;++r) a = fmaf(xdbl[l*40 + r], wd[r], a);
            float dtv = (a > 20.f) ? a : log1pf(__expf(a));
            dtg[l*DIN] = dtv;
        }
    }
    for (int o = t; o < 1024; o += 256){
        int l = o >> 5, q = o & 31;
        float v = xdbl[l*40 + DTR + q];
        size_t g = ((size_t)(b*Lseq + l0 + l))*DSTATE;
        if (q < DSTATE) Bm[g + q] = v;
        else            Cm[g + (q - DSTATE)] = v;
    }
}

// ---------------- Kernel C: scan pass 1, d-per-thread: per-chunk products P[16], partials S[16] ------------
__global__ __launch_bounds__(256) void k_scan1(const float* __restrict__ dt,
        const float* __restrict__ xc, const float* __restrict__ Bm,
        const float* __restrict__ Avw,
        float* __restrict__ Pw, float* __restrict__ Sw){
    __shared__ float Bs[LC*DSTATE];
    int blk = blockIdx.x;              // 2*NC = 256
    int b = blk >> 7, c = blk & 127;
    int l0 = c * LC;
    int t = threadIdx.x;               // = d
    #pragma unroll
    for (int i=0;i<2;++i){
        int e = i*256 + t;
        Bs[e] = Bm[((size_t)(b*Lseq + l0))*DSTATE + e];
    }
    float Av[16];
    #pragma unroll
    for (int s=0;s<16;++s) Av[s] = Avw[s*256 + t];
    __syncthreads();
    float P[16], S[16];
    #pragma unroll
    for (int s=0;s<16;++s){ P[s]=1.f; S[s]=0.f; }
    const float* dtp = dt + ((size_t)(b*Lseq + l0))*DIN + t;
    const float* xcp = xc + ((size_t)(b*Lseq + l0))*DIN + t;
    for (int l=0;l<LC;++l){
        float dtv = dtp[l*DIN];
        float xcv = xcp[l*DIN];
        float dx  = dtv*xcv;
        const float4* Bv = (const float4*)&Bs[l*DSTATE];
        float4 B0 = Bv[0], B1 = Bv[1], B2 = Bv[2], B3 = Bv[3];
        #define ST1(i, bv) { float dA = __expf(dtv*Av[i]); P[i] *= dA; S[i] = fmaf(dA, S[i], dx*(bv)); }
        ST1(0,B0.x) ST1(1,B0.y) ST1(2,B0.z) ST1(3,B0.w)
        ST1(4,B1.x) ST1(5,B1.y) ST1(6,B1.z) ST1(7,B1.w)
        ST1(8,B2.x) ST1(9,B2.y) ST1(10,B2.z) ST1(11,B2.w)
        ST1(12,B3.x) ST1(13,B3.y) ST1(14,B3.z) ST1(15,B3.w)
        #undef ST1
    }
    size_t base = (((size_t)(b*NC + c))*DIN + t)*DSTATE;
    float4* Pp = (float4*)(Pw + base);
    float4* Sp = (float4*)(Sw + base);
    #pragma unroll
    for (int q=0;q<4;++q){
        Pp[q] = make_float4(P[q*4], P[q*4+1], P[q*4+2], P[q*4+3]);
        Sp[q] = make_float4(S[q*4], S[q*4+1], S[q*4+2], S[q*4+3]);
    }
}

// ---------------- Kernel D: pass 2, sequential combine over NC chunks (8192 independent channels) ---------
__global__ __launch_bounds__(256) void k_scan2(const float* __restrict__ Pw,
        const float* __restrict__ Sw, float* __restrict__ Iw){
    int g = blockIdx.x*256 + threadIdx.x;  // 8192
    int b = g >> 12;
    int r = g & 4095;
    float H = 0.f;
    for (int c=0;c<NC;++c){
        size_t idx = ((size_t)(b*NC + c))*4096 + r;
        Iw[idx] = H;
        H = fmaf(Pw[idx], H, Sw[idx]);
    }
}

// ---------------- Kernel E: pass 3, d-per-thread replay; y = h·C + D*xc, gated by silu(z) ------------------
__global__ __launch_bounds__(256) void k_scan3(const float* __restrict__ dt,
        const float* __restrict__ xc, const float* __restrict__ Bm,
        const float* __restrict__ Cm, const float* __restrict__ Avw,
        const float* __restrict__ Dv, const float* __restrict__ zs,
        const float* __restrict__ Iw, float* __restrict__ yg){
    __shared__ float Bs[LC*DSTATE];
    __shared__ float Cs[LC*DSTATE];
    int blk = blockIdx.x;              // 256
    int b = blk >> 7, c = blk & 127;
    int l0 = c * LC;
    int t = threadIdx.x;               // = d
    #pragma unroll
    for (int i=0;i<2;++i){
        int e = i*256 + t;
        size_t g = ((size_t)(b*Lseq + l0))*DSTATE + e;
        Bs[e] = Bm[g];
        Cs[e] = Cm[g];
    }
    float Av[16];
    #pragma unroll
    for (int s=0;s<16;++s) Av[s] = Avw[s*256 + t];
    float h[16];
    {
        size_t base = (((size_t)(b*NC + c))*DIN + t)*DSTATE;
        const float4* Ip = (const float4*)(Iw + base);
        #pragma unroll
        for (int q=0;q<4;++q){
            float4 v = Ip[q];
            h[q*4]=v.x; h[q*4+1]=v.y; h[q*4+2]=v.z; h[q*4+3]=v.w;
        }
    }
    float Dd = Dv[t];
    __syncthreads();
    const float* dtp = dt + ((size_t)(b*Lseq + l0))*DIN + t;
    const float* xcp = xc + ((size_t)(b*Lseq + l0))*DIN + t;
    const float* zsp = zs + ((size_t)(b*Lseq + l0))*DIN + t;
    float*       ygp = yg + ((size_t)(b*Lseq + l0))*DIN + t;
    for (int l=0;l<LC;++l){
        float dtv = dtp[l*DIN];
        float xcv = xcp[l*DIN];
        float zv  = zsp[l*DIN];
        float dx  = dtv*xcv;
        const float4* Bv = (const float4*)&Bs[l*DSTATE];
        const float4* Cv = (const float4*)&Cs[l*DSTATE];
        float4 B0 = Bv[0], B1 = Bv[1], B2 = Bv[2], B3 = Bv[3];
        float4 C0 = Cv[0], C1 = Cv[1], C2 = Cv[2], C3 = Cv[3];
        float y = 0.f;
        #define ST3(i, bv, cv) { float dA = __expf(dtv*Av[i]); h[i] = fmaf(dA, h[i], dx*(bv)); y = fmaf(h[i], (cv), y); }
        ST3(0,B0.x,C0.x) ST3(1,B0.y,C0.y) ST3(2,B0.z,C0.z) ST3(3,B0.w,C0.w)
        ST3(4,B1.x,C1.x) ST3(5,B1.y,C1.y) ST3(6,B1.z,C1.z) ST3(7,B1.w,C1.w)
        ST3(8,B2.x,C2.x) ST3(9,B2.y,C2.y) ST3(10,B2.z,C2.z) ST3(11,B2.w,C2.w)
        ST3(12,B3.x,C3.x) ST3(13,B3.y,C3.y) ST3(14,B3.z,C3.z) ST3(15,B3.w,C3.w)
        #undef ST3
        ygp[l*DIN] = (y + Dd*xcv)*zv;
    }
}

// ---------------- Kernel F: out_proj (256->128) + LayerNorm + transposed NCHW store ------------------------
// 512 blocks: 16 timesteps each. 256 threads: lg=t>>5 (2 l's), cg=t&31 (4 c's) -> 8 outputs/thread.
__global__ __launch_bounds__(256) void k_out(const float* __restrict__ yg,
        const float* __restrict__ Wout, const float* __restrict__ lng,
        const float* __restrict__ lnb, float* __restrict__ out){
    __shared__ float smem[256*18];     // ysm[k][l] stride 18; later reused as os[c][l] stride 20
    int blk = blockIdx.x;
    int b = blk >> 8, l0 = (blk & 255) * 16;
    int t = threadIdx.x;
    // stage yg tile transposed: ysm[k*18+l]
    #pragma unroll
    for (int i=0;i<16;++i){
        int e = i*256 + t;
        int l = e >> 8, k = e & 255;
        smem[k*18 + l] = yg[((size_t)(b*Lseq + l0 + l))*DIN + k];
    }
    __syncthreads();
    int lg = t >> 5, cg = t & 31;
    int l0t = lg*2, c0 = cg*4;
    float acc[2][4];
    #pragma unroll
    for (int i=0;i<2;++i)
        #pragma unroll
        for (int j=0;j<4;++j) acc[i][j]=0.f;
    #pragma unroll 4
    for (int k=0;k<DIN;++k){
        float2 yv = *(const float2*)&smem[k*18 + l0t];
        float4 wv = *(const float4*)&Wout[k*OUTC + c0];
        acc[0][0] = fmaf(yv.x, wv.x, acc[0][0]);
        acc[0][1] = fmaf(yv.x, wv.y, acc[0][1]);
        acc[0][2] = fmaf(yv.x, wv.z, acc[0][2]);
        acc[0][3] = fmaf(yv.x, wv.w, acc[0][3]);
        acc[1][0] = fmaf(yv.y, wv.x, acc[1][0]);
        acc[1][1] = fmaf(yv.y, wv.y, acc[1][1]);
        acc[1][2] = fmaf(yv.y, wv.z, acc[1][2]);
        acc[1][3] = fmaf(yv.y, wv.w, acc[1][3]);
    }
    // LayerNorm over c (128): reduce across the 32 lanes sharing lg (4 c each)
    float4 gm = *(const float4*)&lng[c0];
    float4 bt = *(const float4*)&lnb[c0];
    float o[2][4];
    #pragma unroll
    for (int i=0;i<2;++i){
        float rs = acc[i][0]+acc[i][1]+acc[i][2]+acc[i][3];
        #pragma unroll
        for (int m=16;m>0;m>>=1) rs += __shfl_xor(rs, m, 64);
        float mu = rs * (1.f/128.f);
        float d0 = acc[i][0]-mu, d1 = acc[i][1]-mu, d2 = acc[i][2]-mu, d3 = acc[i][3]-mu;
        float sq = d0*d0+d1*d1+d2*d2+d3*d3;
        #pragma unroll
        for (int m=16;m>0;m>>=1) sq += __shfl_xor(sq, m, 64);
        float rstd = rsqrtf(sq * (1.f/128.f) + 1e-5f);
        o[i][0] = d0*rstd*gm.x + bt.x;
        o[i][1] = d1*rstd*gm.y + bt.y;
        o[i][2] = d2*rstd*gm.z + bt.z;
        o[i][3] = d3*rstd*gm.w + bt.w;
    }
    __syncthreads();                   // done reading ysm; reuse smem as os[c*20+l]
    #pragma unroll
    for (int i=0;i<2;++i)
        #pragma unroll
        for (int j=0;j<4;++j) smem[(c0+j)*20 + l0t + i] = o[i][j];
    __syncthreads();
    // store: row c = t>>1, half = t&1 -> 8 consecutive l (32B) per lane
    {
        int c = t >> 1, half = t & 1;
        float4 v0 = *(const float4*)&smem[c*20 + half*8];
        float4 v1 = *(const float4*)&smem[c*20 + half*8 + 4];
        float* op = out + ((size_t)(b*OUTC + c))*Lseq + l0 + half*8;
        *(float4*)op       = v0;
        *(float4*)(op + 4) = v1;
    }
}

extern "C" void kernel_launch(void* const* d_in, const int* in_sizes, int n_in,
                              void* d_out, int out_size, void* d_ws, size_t ws_size,
                              hipStream_t stream) {
    const float* x1    = (const float*)d_in[0];
    const float* Win   = (const float*)d_in[1];
    const float* convw = (const float*)d_in[2];
    const float* convb = (const float*)d_in[3];
    const float* Wx    = (const float*)d_in[4];
    const float* Wdt   = (const float*)d_in[5];
    const float* bdt   = (const float*)d_in[6];
    const float* Alog  = (const float*)d_in[7];
    const float* Dv    = (const float*)d_in[8];
    const float* Wout  = (const float*)d_in[9];
    const float* lng   = (const float*)d_in[10];
    const float* lnb   = (const float*)d_in[11];
    float* out = (float*)d_out;

    float* ws  = (float*)d_ws;
    float* xin = ws;                  // 2,097,152 (reused as yg after conv)
    float* zs  = xin + 2097152;       // 2,097,152
    float* xc  = zs  + 2097152;       // 2,097,152
    float* dt  = xc  + 2097152;       // 2,097,152
    float* Bm  = dt  + 2097152;       //   131,072
    float* Cm  = Bm  + 131072;        //   131,072
    float* Pw  = Cm  + 131072;        // 1,048,576
    float* Sw  = Pw  + 1048576;       // 1,048,576
    float* Iw  = Sw  + 1048576;       // 1,048,576
    float* Avw = Iw  + 1048576;       //     4,096   (~47.2 MB total)
    float* yg  = xin;                 // alias: xin dead after k_conv_proj

    k_inproj   <<<1024, 256, 0, stream>>>(x1, Win, xin, zs);
    k_prep     <<<16,   256, 0, stream>>>(Alog, Avw);
    k_conv_proj<<<256,  256, 0, stream>>>(xin, convw, convb, Wx, Wdt, bdt, xc, dt, Bm, Cm);
    k_scan1    <<<256,  256, 0, stream>>>(dt, xc, Bm, Avw, Pw, Sw);
    k_scan2    <<<32,   256, 0, stream>>>(Pw, Sw, Iw);
    k_scan3    <<<256,  256, 0, stream>>>(dt, xc, Bm, Cm, Avw, Dv, zs, Iw, yg);
    k_out      <<<512,  256, 0, stream>>>(yg, Wout, lng, lnb, out);
}

// Round 4
// 209.839 us; speedup vs baseline: 1.8047x; 1.0002x over previous
//
#include <hip/hip_runtime.h>
#include <math.h>

#define B_ 2
#define DMODEL 128
#define DIN 256
#define DSTATE 16
#define DTR 8
#define OUTC 128
#define Lseq 4096
#define NC 128
#define LC 32

__device__ __forceinline__ float siluf(float x){ return x / (1.f + __expf(-x)); }

// ---------------- Kernel A: in_proj  x(b,L,128) @ W_in(128,512) -> xin(b,L,256), zs=silu(z) ----------------
__global__ __launch_bounds__(256) void k_inproj(const float* __restrict__ x1,
        const float* __restrict__ Win, float* __restrict__ xin, float* __restrict__ zs){
    __shared__ float xt[8*DMODEL];              // [c][p] layout: xt[c*8+p]
    int blk = blockIdx.x;
    int b = blk >> 9;
    int l0 = (blk & 511) * 8;
    int t = threadIdx.x;
    const float* xb = x1 + (size_t)b * DMODEL * Lseq;
    #pragma unroll
    for (int i = 0; i < 4; ++i){
        int e = t + i*256;
        int c = e >> 3, p = e & 7;
        xt[e] = xb[(size_t)c*Lseq + l0 + p];
    }
    __syncthreads();
    float acc0[8], acc1[8];
    #pragma unroll
    for (int p=0;p<8;++p){acc0[p]=0.f;acc1[p]=0.f;}
    for (int k=0;k<DMODEL;++k){
        float w0 = Win[k*512 + t];
        float w1 = Win[k*512 + t + 256];
        #pragma unroll
        for (int p=0;p<8;++p){
            float xv = xt[k*8 + p];
            acc0[p] = fmaf(xv, w0, acc0[p]);
            acc1[p] = fmaf(xv, w1, acc1[p]);
        }
    }
    #pragma unroll
    for (int p=0;p<8;++p){
        size_t base = ((size_t)(b*Lseq + l0 + p))*DIN;
        xin[base + t] = acc0[p];
        zs[base + t]  = siluf(acc1[p]);
    }
}

// ---------------- Kernel B: 32 timesteps per block; conv+silu, x_proj GEMM-style, dt_proj ------------------
__global__ __launch_bounds__(256) void k_conv_proj(const float* __restrict__ xin,
        const float* __restrict__ convw, const float* __restrict__ convb,
        const float* __restrict__ Wx, const float* __restrict__ Wdt,
        const float* __restrict__ bdt,
        float* __restrict__ xc, float* __restrict__ dt,
        float* __restrict__ Bm, float* __restrict__ Cm){
    __shared__ float xcs[32*257];
    __shared__ float xdbl[32*40];
    int blk = blockIdx.x;
    int b  = blk >> 7;
    int l0 = (blk & 127) << 5;
    int t  = threadIdx.x;

    float w0 = convw[t*4+0], w1 = convw[t*4+1], w2 = convw[t*4+2], w3 = convw[t*4+3];
    float bb = convb[t];
    const float* xinb = xin + ((size_t)(b*Lseq + l0))*DIN + t;
    float x3, x2, x1;
    if (l0 == 0) { x3 = x2 = x1 = 0.f; }
    else { x3 = xinb[-3*DIN]; x2 = xinb[-2*DIN]; x1 = xinb[-1*DIN]; }
    float* xcg = xc + ((size_t)(b*Lseq + l0))*DIN + t;
    #pragma unroll 4
    for (int l = 0; l < 32; ++l){
        float x0 = xinb[l*DIN];
        float acc = bb;
        acc = fmaf(x3, w0, acc);
        acc = fmaf(x2, w1, acc);
        acc = fmaf(x1, w2, acc);
        acc = fmaf(x0, w3, acc);
        float v = siluf(acc);
        xcs[l*257 + t] = v;
        xcg[l*DIN] = v;
        x3 = x2; x2 = x1; x1 = x0;
    }
    __syncthreads();

    {
        int jg = t & 7;
        int lg = t >> 3;
        int j0 = jg * 5;
        float a0=0.f, a1=0.f, a2=0.f, a3=0.f, a4=0.f;
        const float* xrow = xcs + lg*257;
        const float* wbase = Wx + j0;
        #pragma unroll 8
        for (int d = 0; d < 256; ++d){
            float xv = xrow[d];
            const float* wr = wbase + d*40;
            a0 = fmaf(xv, wr[0], a0);
            a1 = fmaf(xv, wr[1], a1);
            a2 = fmaf(xv, wr[2], a2);
            a3 = fmaf(xv, wr[3], a3);
            a4 = fmaf(xv, wr[4], a4);
        }
        float* xo = xdbl + lg*40 + j0;
        xo[0]=a0; xo[1]=a1; xo[2]=a2; xo[3]=a3; xo[4]=a4;
    }
    __syncthreads();

    {
        float wd[DTR];
        #pragma unroll
        for (int r=0;r<DTR;++r) wd[r] = Wdt[r*DIN + t];
        float bv = bdt[t];
        float* dtg = dt + ((size_t)(b*Lseq + l0))*DIN + t;
        #pragma unroll 4
        for (int l=0;l<32;++l){
            float a = bv;
            #pragma unroll
            for (int r=0;r<DTR;++r) a = fmaf(xdbl[l*40 + r], wd[r], a);
            float dtv = (a > 20.f) ? a : log1pf(__expf(a));
            dtg[l*DIN] = dtv;
        }
    }
    for (int o = t; o < 1024; o += 256){
        int l = o >> 5, q = o & 31;
        float v = xdbl[l*40 + DTR + q];
        size_t g = ((size_t)(b*Lseq + l0 + l))*DSTATE;
        if (q < DSTATE) Bm[g + q] = v;
        else            Cm[g + (q - DSTATE)] = v;
    }
}

// ---------------- Kernel C: scan pass 1, d-per-thread; writes (P,S) interleaved, chunk-major --------------
// PSw layout: float2 at index (b*4096 + r)*NC + c, where r = d*16 + s.
__global__ __launch_bounds__(256) void k_scan1(const float* __restrict__ dt,
        const float* __restrict__ xc, const float* __restrict__ Bm,
        const float* __restrict__ Alog, float2* __restrict__ PSw){
    __shared__ float Bs[LC*DSTATE];
    int blk = blockIdx.x;              // 2*NC = 256
    int b = blk >> 7, c = blk & 127;
    int l0 = c * LC;
    int t = threadIdx.x;               // = d
    #pragma unroll
    for (int i=0;i<2;++i){
        int e = i*256 + t;
        Bs[e] = Bm[((size_t)(b*Lseq + l0))*DSTATE + e];
    }
    float Av[16];
    {
        const float4* Ap = (const float4*)(Alog + t*DSTATE);
        #pragma unroll
        for (int q=0;q<4;++q){
            float4 a = Ap[q];
            Av[q*4]   = -__expf(a.x);
            Av[q*4+1] = -__expf(a.y);
            Av[q*4+2] = -__expf(a.z);
            Av[q*4+3] = -__expf(a.w);
        }
    }
    __syncthreads();
    float P[16], S[16];
    #pragma unroll
    for (int s=0;s<16;++s){ P[s]=1.f; S[s]=0.f; }
    const float* dtp = dt + ((size_t)(b*Lseq + l0))*DIN + t;
    const float* xcp = xc + ((size_t)(b*Lseq + l0))*DIN + t;
    for (int l=0;l<LC;++l){
        float dtv = dtp[l*DIN];
        float xcv = xcp[l*DIN];
        float dx  = dtv*xcv;
        const float4* Bv = (const float4*)&Bs[l*DSTATE];
        float4 B0 = Bv[0], B1 = Bv[1], B2 = Bv[2], B3 = Bv[3];
        #define ST1(i, bv) { float dA = __expf(dtv*Av[i]); P[i] *= dA; S[i] = fmaf(dA, S[i], dx*(bv)); }
        ST1(0,B0.x) ST1(1,B0.y) ST1(2,B0.z) ST1(3,B0.w)
        ST1(4,B1.x) ST1(5,B1.y) ST1(6,B1.z) ST1(7,B1.w)
        ST1(8,B2.x) ST1(9,B2.y) ST1(10,B2.z) ST1(11,B2.w)
        ST1(12,B3.x) ST1(13,B3.y) ST1(14,B3.z) ST1(15,B3.w)
        #undef ST1
    }
    #pragma unroll
    for (int s=0;s<16;++s){
        size_t r = (size_t)b*4096 + t*DSTATE + s;
        PSw[r*NC + c] = make_float2(P[s], S[s]);
    }
}

// ---------------- Kernel D: pass 2, wave-per-channel parallel shuffle scan over 128 chunks ----------------
// Iw layout: float at (b*4096 + r)*NC + c.
__global__ __launch_bounds__(256) void k_scan2(const float2* __restrict__ PSw,
        float* __restrict__ Iw){
    int wv = blockIdx.x*4 + (threadIdx.x >> 6);   // 8192 waves = one channel each
    int lane = threadIdx.x & 63;
    int b = wv >> 12, r = wv & 4095;
    const float4* PS4 = (const float4*)PSw;       // (P0,S0,P1,S1) per lane
    float4 v = PS4[((size_t)b*4096 + r)*64 + lane];
    float p0 = v.x, s0 = v.y;
    // lane aggregate over its two chunks
    float P = p0 * v.z;
    float S = fmaf(s0, v.z, v.w);
    // inclusive Hillis-Steele scan, combine(left,right) = (Pl*Pr, Sl*Pr + Sr)
    #define STEP(off) { float Pp = __shfl_up(P, off, 64); float Sp = __shfl_up(S, off, 64); \
                        if (lane >= off){ S = fmaf(Sp, P, S); P *= Pp; } }
    STEP(1) STEP(2) STEP(4) STEP(8) STEP(16) STEP(32)
    #undef STEP
    // exclusive prefix offset (h0 = 0 -> incoming h = S of prefix)
    float Se = __shfl_up(S, 1, 64);
    if (lane == 0) Se = 0.f;
    float I0 = Se;
    float I1 = fmaf(p0, Se, s0);
    float2* Iw2 = (float2*)Iw;
    Iw2[((size_t)b*4096 + r)*64 + lane] = make_float2(I0, I1);
}

// ---------------- Kernel E: fused scan pass 3 + out_proj + LayerNorm + NCHW store -------------------------
__global__ __launch_bounds__(256) void k_scan3out(const float* __restrict__ dt,
        const float* __restrict__ xc, const float* __restrict__ Bm,
        const float* __restrict__ Cm, const float* __restrict__ Alog,
        const float* __restrict__ Dv, const float* __restrict__ zs,
        const float* __restrict__ Iw,
        const float* __restrict__ Wout, const float* __restrict__ lng,
        const float* __restrict__ lnb, float* __restrict__ out){
    __shared__ float ysm[256*34];      // [d][l] stride 34
    __shared__ float os[128*34];       // [c][l] stride 34
    __shared__ float Bs[LC*DSTATE];
    __shared__ float Cs[LC*DSTATE];
    int blk = blockIdx.x;              // 256 = b x 128 l-chunks
    int b = blk >> 7, c = blk & 127;
    int l0 = c * LC;
    int t = threadIdx.x;               // = d in scan phase
    #pragma unroll
    for (int i=0;i<2;++i){
        int e = i*256 + t;
        size_t g = ((size_t)(b*Lseq + l0))*DSTATE + e;
        Bs[e] = Bm[g];
        Cs[e] = Cm[g];
    }
    float Av[16];
    {
        const float4* Ap = (const float4*)(Alog + t*DSTATE);
        #pragma unroll
        for (int q=0;q<4;++q){
            float4 a = Ap[q];
            Av[q*4]   = -__expf(a.x);
            Av[q*4+1] = -__expf(a.y);
            Av[q*4+2] = -__expf(a.z);
            Av[q*4+3] = -__expf(a.w);
        }
    }
    float h[16];
    #pragma unroll
    for (int s=0;s<16;++s)
        h[s] = Iw[((size_t)b*4096 + t*DSTATE + s)*NC + c];
    float Dd = Dv[t];
    __syncthreads();
    const float* dtp = dt + ((size_t)(b*Lseq + l0))*DIN + t;
    const float* xcp = xc + ((size_t)(b*Lseq + l0))*DIN + t;
    const float* zsp = zs + ((size_t)(b*Lseq + l0))*DIN + t;
    for (int l=0;l<LC;++l){
        float dtv = dtp[l*DIN];
        float xcv = xcp[l*DIN];
        float zv  = zsp[l*DIN];
        float dx  = dtv*xcv;
        const float4* Bv = (const float4*)&Bs[l*DSTATE];
        const float4* Cv = (const float4*)&Cs[l*DSTATE];
        float4 B0 = Bv[0], B1 = Bv[1], B2 = Bv[2], B3 = Bv[3];
        float4 C0 = Cv[0], C1 = Cv[1], C2 = Cv[2], C3 = Cv[3];
        float y = 0.f;
        #define ST3(i, bv, cv) { float dA = __expf(dtv*Av[i]); h[i] = fmaf(dA, h[i], dx*(bv)); y = fmaf(h[i], (cv), y); }
        ST3(0,B0.x,C0.x) ST3(1,B0.y,C0.y) ST3(2,B0.z,C0.z) ST3(3,B0.w,C0.w)
        ST3(4,B1.x,C1.x) ST3(5,B1.y,C1.y) ST3(6,B1.z,C1.z) ST3(7,B1.w,C1.w)
        ST3(8,B2.x,C2.x) ST3(9,B2.y,C2.y) ST3(10,B2.z,C2.z) ST3(11,B2.w,C2.w)
        ST3(12,B3.x,C3.x) ST3(13,B3.y,C3.y) ST3(14,B3.z,C3.z) ST3(15,B3.w,C3.w)
        #undef ST3
        ysm[t*34 + l] = (y + Dd*xcv)*zv;
    }
    __syncthreads();
    // ---- out_proj: 32l x 128c tile. thread: lg=t>>5 -> l pairs {l0t,l0t+1,l0t+16,l0t+17}, cg=t&31 -> 4 c
    int lg = t >> 5, cg = t & 31;
    int l0t = lg*2, c0 = cg*4;
    float acc[4][4];
    #pragma unroll
    for (int i=0;i<4;++i)
        #pragma unroll
        for (int j=0;j<4;++j) acc[i][j]=0.f;
    #pragma unroll 4
    for (int k=0;k<DIN;++k){
        float2 ya = *(const float2*)&ysm[k*34 + l0t];
        float2 yb = *(const float2*)&ysm[k*34 + l0t + 16];
        float4 wv = *(const float4*)&Wout[k*OUTC + c0];
        acc[0][0]=fmaf(ya.x,wv.x,acc[0][0]); acc[0][1]=fmaf(ya.x,wv.y,acc[0][1]);
        acc[0][2]=fmaf(ya.x,wv.z,acc[0][2]); acc[0][3]=fmaf(ya.x,wv.w,acc[0][3]);
        acc[1][0]=fmaf(ya.y,wv.x,acc[1][0]); acc[1][1]=fmaf(ya.y,wv.y,acc[1][1]);
        acc[1][2]=fmaf(ya.y,wv.z,acc[1][2]); acc[1][3]=fmaf(ya.y,wv.w,acc[1][3]);
        acc[2][0]=fmaf(yb.x,wv.x,acc[2][0]); acc[2][1]=fmaf(yb.x,wv.y,acc[2][1]);
        acc[2][2]=fmaf(yb.x,wv.z,acc[2][2]); acc[2][3]=fmaf(yb.x,wv.w,acc[2][3]);
        acc[3][0]=fmaf(yb.y,wv.x,acc[3][0]); acc[3][1]=fmaf(yb.y,wv.y,acc[3][1]);
        acc[3][2]=fmaf(yb.y,wv.z,acc[3][2]); acc[3][3]=fmaf(yb.y,wv.w,acc[3][3]);
    }
    // LayerNorm over c: reduce across 32 lanes (xor masks < 32 stay in half-wave)
    float4 gm = *(const float4*)&lng[c0];
    float4 bt = *(const float4*)&lnb[c0];
    #pragma unroll
    for (int i=0;i<4;++i){
        int lidx = l0t + (i & 1) + (i >> 1)*16;
        float rs = acc[i][0]+acc[i][1]+acc[i][2]+acc[i][3];
        #pragma unroll
        for (int m=16;m>0;m>>=1) rs += __shfl_xor(rs, m, 64);
        float mu = rs * (1.f/128.f);
        float d0 = acc[i][0]-mu, d1 = acc[i][1]-mu, d2 = acc[i][2]-mu, d3 = acc[i][3]-mu;
        float sq = d0*d0+d1*d1+d2*d2+d3*d3;
        #pragma unroll
        for (int m=16;m>0;m>>=1) sq += __shfl_xor(sq, m, 64);
        float rstd = rsqrtf(sq * (1.f/128.f) + 1e-5f);
        os[(c0+0)*34 + lidx] = d0*rstd*gm.x + bt.x;
        os[(c0+1)*34 + lidx] = d1*rstd*gm.y + bt.y;
        os[(c0+2)*34 + lidx] = d2*rstd*gm.z + bt.z;
        os[(c0+3)*34 + lidx] = d3*rstd*gm.w + bt.w;
    }
    __syncthreads();
    // store: c = t>>1, sel = t&1 -> 16 consecutive l (64B) per lane
    {
        int cc = t >> 1, sel = t & 1;
        float* op = out + ((size_t)(b*OUTC + cc))*Lseq + l0 + sel*16;
        const float* ip = &os[cc*34 + sel*16];
        #pragma unroll
        for (int q=0;q<4;++q)
            *(float4*)(op + q*4) = *(const float4*)(ip + q*4);
    }
}

extern "C" void kernel_launch(void* const* d_in, const int* in_sizes, int n_in,
                              void* d_out, int out_size, void* d_ws, size_t ws_size,
                              hipStream_t stream) {
    const float* x1    = (const float*)d_in[0];
    const float* Win   = (const float*)d_in[1];
    const float* convw = (const float*)d_in[2];
    const float* convb = (const float*)d_in[3];
    const float* Wx    = (const float*)d_in[4];
    const float* Wdt   = (const float*)d_in[5];
    const float* bdt   = (const float*)d_in[6];
    const float* Alog  = (const float*)d_in[7];
    const float* Dv    = (const float*)d_in[8];
    const float* Wout  = (const float*)d_in[9];
    const float* lng   = (const float*)d_in[10];
    const float* lnb   = (const float*)d_in[11];
    float* out = (float*)d_out;

    float* ws  = (float*)d_ws;
    float* xin = ws;                  // 2,097,152 floats
    float* zs  = xin + 2097152;       // 2,097,152
    float* xc  = zs  + 2097152;       // 2,097,152
    float* dt  = xc  + 2097152;       // 2,097,152
    float* Bm  = dt  + 2097152;       //   131,072
    float* Cm  = Bm  + 131072;        //   131,072
    float2* PSw = (float2*)(Cm + 131072);   // 1,048,576 float2 = 2,097,152 floats
    float* Iw  = (float*)(PSw + 1048576);   // 1,048,576 floats (~45 MB total)

    k_inproj   <<<1024, 256, 0, stream>>>(x1, Win, xin, zs);
    k_conv_proj<<<256,  256, 0, stream>>>(xin, convw, convb, Wx, Wdt, bdt, xc, dt, Bm, Cm);
    k_scan1    <<<256,  256, 0, stream>>>(dt, xc, Bm, Alog, PSw);
    k_scan2    <<<2048, 256, 0, stream>>>(PSw, Iw);
    k_scan3out <<<256,  256, 0, stream>>>(dt, xc, Bm, Cm, Alog, Dv, zs, Iw,
                                          Wout, lng, lnb, out);
}

// Round 5
// 190.531 us; speedup vs baseline: 1.9876x; 1.1013x over previous
//
#include <hip/hip_runtime.h>
#include <math.h>

#define B_ 2
#define DMODEL 128
#define DIN 256
#define DSTATE 16
#define DTR 8
#define OUTC 128
#define Lseq 4096
#define NC 256          // chunks per batch
#define LC 16           // timesteps per chunk

__device__ __forceinline__ float siluf(float x){ return x / (1.f + __expf(-x)); }

// ---------------- Kernel A: in_proj  x(b,L,128) @ W_in(128,512) -> xin(b,L,256), zs=silu(z) ----------------
// 512 blocks x 16 timesteps: halves per-block Win traffic vs 8-l blocks.
__global__ __launch_bounds__(256) void k_inproj(const float* __restrict__ x1,
        const float* __restrict__ Win, float* __restrict__ xin, float* __restrict__ zs){
    __shared__ float xt[16*DMODEL];             // xt[c*16+p]
    int blk = blockIdx.x;
    int b = blk >> 8;
    int l0 = (blk & 255) * 16;
    int t = threadIdx.x;
    const float* xb = x1 + (size_t)b * DMODEL * Lseq;
    #pragma unroll
    for (int i = 0; i < 8; ++i){
        int e = t + i*256;
        int c = e >> 4, p = e & 15;
        xt[e] = xb[(size_t)c*Lseq + l0 + p];
    }
    __syncthreads();
    float acc0[16], acc1[16];
    #pragma unroll
    for (int p=0;p<16;++p){acc0[p]=0.f;acc1[p]=0.f;}
    for (int k=0;k<DMODEL;++k){
        float w0 = Win[k*512 + t];
        float w1 = Win[k*512 + t + 256];
        #pragma unroll
        for (int p=0;p<16;++p){
            float xv = xt[k*16 + p];
            acc0[p] = fmaf(xv, w0, acc0[p]);
            acc1[p] = fmaf(xv, w1, acc1[p]);
        }
    }
    #pragma unroll
    for (int p=0;p<16;++p){
        size_t base = ((size_t)(b*Lseq + l0 + p))*DIN;
        xin[base + t] = acc0[p];
        zs[base + t]  = siluf(acc1[p]);
    }
}

// ---------------- Kernel B: conv+silu, x_proj, dt_proj, FUSED scan pass 1 (two 16-l chunks) ---------------
// PSw layout: float2 at (b*NC + chunk)*4096 + d*16 + s  -> conv writes 128B/thread runs, coalesced.
__global__ __launch_bounds__(256) void k_conv_scan1(const float* __restrict__ xin,
        const float* __restrict__ convw, const float* __restrict__ convb,
        const float* __restrict__ Wx, const float* __restrict__ Wdt,
        const float* __restrict__ bdt, const float* __restrict__ Alog,
        float* __restrict__ xc, float* __restrict__ dt,
        float* __restrict__ Bm, float* __restrict__ Cm, float2* __restrict__ PSw){
    __shared__ float xcs[32*257];
    __shared__ float xdbl[32*40];
    int blk = blockIdx.x;              // 256 = b x 128 (32-l blocks)
    int b  = blk >> 7;
    int cb = blk & 127;
    int l0 = cb << 5;
    int t  = threadIdx.x;

    // ---- phase 1: causal depthwise conv + silu ----
    float w0 = convw[t*4+0], w1 = convw[t*4+1], w2 = convw[t*4+2], w3 = convw[t*4+3];
    float bb = convb[t];
    const float* xinb = xin + ((size_t)(b*Lseq + l0))*DIN + t;
    float x3, x2, x1;
    if (l0 == 0) { x3 = x2 = x1 = 0.f; }
    else { x3 = xinb[-3*DIN]; x2 = xinb[-2*DIN]; x1 = xinb[-1*DIN]; }
    float* xcg = xc + ((size_t)(b*Lseq + l0))*DIN + t;
    #pragma unroll 4
    for (int l = 0; l < 32; ++l){
        float x0 = xinb[l*DIN];
        float acc = bb;
        acc = fmaf(x3, w0, acc);
        acc = fmaf(x2, w1, acc);
        acc = fmaf(x1, w2, acc);
        acc = fmaf(x0, w3, acc);
        float v = siluf(acc);
        xcs[l*257 + t] = v;
        xcg[l*DIN] = v;
        x3 = x2; x2 = x1; x1 = x0;
    }
    __syncthreads();

    // ---- phase 2: x_proj ----
    {
        int jg = t & 7;
        int lg = t >> 3;
        int j0 = jg * 5;
        float a0=0.f, a1=0.f, a2=0.f, a3=0.f, a4=0.f;
        const float* xrow = xcs + lg*257;
        const float* wbase = Wx + j0;
        #pragma unroll 8
        for (int d = 0; d < 256; ++d){
            float xv = xrow[d];
            const float* wr = wbase + d*40;
            a0 = fmaf(xv, wr[0], a0);
            a1 = fmaf(xv, wr[1], a1);
            a2 = fmaf(xv, wr[2], a2);
            a3 = fmaf(xv, wr[3], a3);
            a4 = fmaf(xv, wr[4], a4);
        }
        float* xo = xdbl + lg*40 + j0;
        xo[0]=a0; xo[1]=a1; xo[2]=a2; xo[3]=a3; xo[4]=a4;
    }
    __syncthreads();

    // ---- phase 3: dt_proj + softplus + fused scan pass 1 ----
    {
        float wd[DTR];
        #pragma unroll
        for (int r=0;r<DTR;++r) wd[r] = Wdt[r*DIN + t];
        float bv = bdt[t];
        float Av[16];
        {
            const float4* Ap = (const float4*)(Alog + t*DSTATE);
            #pragma unroll
            for (int q=0;q<4;++q){
                float4 a = Ap[q];
                Av[q*4]   = -__expf(a.x);
                Av[q*4+1] = -__expf(a.y);
                Av[q*4+2] = -__expf(a.z);
                Av[q*4+3] = -__expf(a.w);
            }
        }
        float P[16], S[16];
        #pragma unroll
        for (int s=0;s<16;++s){ P[s]=1.f; S[s]=0.f; }
        float* dtg = dt + ((size_t)(b*Lseq + l0))*DIN + t;
        #pragma unroll 4
        for (int l=0;l<32;++l){
            float a = bv;
            #pragma unroll
            for (int r=0;r<DTR;++r) a = fmaf(xdbl[l*40 + r], wd[r], a);
            float dtv = (a > 20.f) ? a : log1pf(__expf(a));
            dtg[l*DIN] = dtv;
            float xcv = xcs[l*257 + t];
            float dx  = dtv*xcv;
            const float4* Bv = (const float4*)&xdbl[l*40 + DTR];
            float4 B0 = Bv[0], B1 = Bv[1], B2 = Bv[2], B3 = Bv[3];
            #define ST1(i, bval) { float dA = __expf(dtv*Av[i]); P[i] *= dA; S[i] = fmaf(dA, S[i], dx*(bval)); }
            ST1(0,B0.x) ST1(1,B0.y) ST1(2,B0.z) ST1(3,B0.w)
            ST1(4,B1.x) ST1(5,B1.y) ST1(6,B1.z) ST1(7,B1.w)
            ST1(8,B2.x) ST1(9,B2.y) ST1(10,B2.z) ST1(11,B2.w)
            ST1(12,B3.x) ST1(13,B3.y) ST1(14,B3.z) ST1(15,B3.w)
            #undef ST1
            if (l == 15){
                float2* ps = PSw + ((size_t)(b*NC + cb*2))*4096 + t*DSTATE;
                #pragma unroll
                for (int s=0;s<16;++s){ ps[s] = make_float2(P[s], S[s]); P[s]=1.f; S[s]=0.f; }
            }
        }
        float2* ps = PSw + ((size_t)(b*NC + cb*2 + 1))*4096 + t*DSTATE;
        #pragma unroll
        for (int s=0;s<16;++s) ps[s] = make_float2(P[s], S[s]);
    }
    // ---- B/C extraction ----
    for (int o = t; o < 1024; o += 256){
        int l = o >> 5, q = o & 31;
        float v = xdbl[l*40 + DTR + q];
        size_t g = ((size_t)(b*Lseq + l0 + l))*DSTATE;
        if (q < DSTATE) Bm[g + q] = v;
        else            Cm[g + (q - DSTATE)] = v;
    }
}

// ---------------- Kernel C: pass 2, serial chunk combine, fully coalesced streams -------------------------
// Iw layout: float at (b*NC + chunk)*4096 + r  (state ENTERING chunk).
__global__ __launch_bounds__(256) void k_scan2(const float2* __restrict__ PSw,
        float* __restrict__ Iw){
    int g = blockIdx.x*256 + threadIdx.x;  // 8192 channels
    int b = g >> 12;
    int r = g & 4095;
    float H = 0.f;
    #pragma unroll 8
    for (int c=0;c<NC;++c){
        size_t idx = ((size_t)(b*NC + c))*4096 + r;
        float2 ps = PSw[idx];
        Iw[idx] = H;
        H = fmaf(ps.x, H, ps.y);
    }
}

// ---------------- Kernel D: fused scan pass 3 + out_proj + LayerNorm + NCHW store -------------------------
// 512 blocks (b x 256 chunks of 16 l), 256 threads.
__global__ __launch_bounds__(256) void k_scan3out(const float* __restrict__ dt,
        const float* __restrict__ xc, const float* __restrict__ zs,
        const float* __restrict__ Bm, const float* __restrict__ Cm,
        const float* __restrict__ Alog, const float* __restrict__ Dv,
        const float* __restrict__ Iw,
        const float* __restrict__ Wout, const float* __restrict__ lng,
        const float* __restrict__ lnb, float* __restrict__ out){
    __shared__ float ysm[256*18];      // [d][l] stride 18
    __shared__ float os[128*18];       // [c][l] stride 18
    __shared__ float Bs[LC*DSTATE];    // 256
    __shared__ float Cs[LC*DSTATE];
    int blk = blockIdx.x;
    int b = blk >> 8, c = blk & 255;
    int l0 = c * LC;
    int t = threadIdx.x;               // = d in scan phase
    size_t gb = (size_t)(b*Lseq + l0);
    Bs[t] = Bm[gb*DSTATE + t];
    Cs[t] = Cm[gb*DSTATE + t];
    float Av[16];
    {
        const float4* Ap = (const float4*)(Alog + t*DSTATE);
        #pragma unroll
        for (int q=0;q<4;++q){
            float4 a = Ap[q];
            Av[q*4]   = -__expf(a.x);
            Av[q*4+1] = -__expf(a.y);
            Av[q*4+2] = -__expf(a.z);
            Av[q*4+3] = -__expf(a.w);
        }
    }
    float h[16];
    {
        const float4* Ip = (const float4*)(Iw + ((size_t)(b*NC + c))*4096 + t*DSTATE);
        #pragma unroll
        for (int q=0;q<4;++q){
            float4 v = Ip[q];
            h[q*4]=v.x; h[q*4+1]=v.y; h[q*4+2]=v.z; h[q*4+3]=v.w;
        }
    }
    float Dd = Dv[t];
    // register-stage all 48 loads (independent -> single latency window)
    float dtv[LC], xcv[LC], zvv[LC];
    {
        const float* dtp = dt + gb*DIN + t;
        const float* xcp = xc + gb*DIN + t;
        const float* zsp = zs + gb*DIN + t;
        #pragma unroll
        for (int l=0;l<LC;++l){
            dtv[l] = dtp[l*DIN];
            xcv[l] = xcp[l*DIN];
            zvv[l] = zsp[l*DIN];
        }
    }
    __syncthreads();
    #pragma unroll
    for (int l=0;l<LC;++l){
        float dtl = dtv[l];
        float dx  = dtl*xcv[l];
        const float4* Bv = (const float4*)&Bs[l*DSTATE];
        const float4* Cv = (const float4*)&Cs[l*DSTATE];
        float4 B0 = Bv[0], B1 = Bv[1], B2 = Bv[2], B3 = Bv[3];
        float4 C0 = Cv[0], C1 = Cv[1], C2 = Cv[2], C3 = Cv[3];
        float y = 0.f;
        #define ST3(i, bval, cval) { float dA = __expf(dtl*Av[i]); h[i] = fmaf(dA, h[i], dx*(bval)); y = fmaf(h[i], (cval), y); }
        ST3(0,B0.x,C0.x) ST3(1,B0.y,C0.y) ST3(2,B0.z,C0.z) ST3(3,B0.w,C0.w)
        ST3(4,B1.x,C1.x) ST3(5,B1.y,C1.y) ST3(6,B1.z,C1.z) ST3(7,B1.w,C1.w)
        ST3(8,B2.x,C2.x) ST3(9,B2.y,C2.y) ST3(10,B2.z,C2.z) ST3(11,B2.w,C2.w)
        ST3(12,B3.x,C3.x) ST3(13,B3.y,C3.y) ST3(14,B3.z,C3.z) ST3(15,B3.w,C3.w)
        #undef ST3
        ysm[t*18 + l] = (y + Dd*xcv[l])*zvv[l];
    }
    __syncthreads();
    // ---- out_proj: 16l x 128c tile. lg=t>>5 -> l {lg*2, lg*2+1}; cg=t&31 -> 4 c.
    int lg = t >> 5, cg = t & 31;
    int l0t = lg*2, c0 = cg*4;
    float acc[2][4];
    #pragma unroll
    for (int i=0;i<2;++i)
        #pragma unroll
        for (int j=0;j<4;++j) acc[i][j]=0.f;
    #pragma unroll 4
    for (int k=0;k<DIN;++k){
        float2 yv = *(const float2*)&ysm[k*18 + l0t];
        float4 wv = *(const float4*)&Wout[k*OUTC + c0];
        acc[0][0]=fmaf(yv.x,wv.x,acc[0][0]); acc[0][1]=fmaf(yv.x,wv.y,acc[0][1]);
        acc[0][2]=fmaf(yv.x,wv.z,acc[0][2]); acc[0][3]=fmaf(yv.x,wv.w,acc[0][3]);
        acc[1][0]=fmaf(yv.y,wv.x,acc[1][0]); acc[1][1]=fmaf(yv.y,wv.y,acc[1][1]);
        acc[1][2]=fmaf(yv.y,wv.z,acc[1][2]); acc[1][3]=fmaf(yv.y,wv.w,acc[1][3]);
    }
    // LayerNorm over c: reduce across the 32 lanes sharing this l (xor<=16 stays in half-wave)
    float4 gm = *(const float4*)&lng[c0];
    float4 bt = *(const float4*)&lnb[c0];
    #pragma unroll
    for (int i=0;i<2;++i){
        float rs = acc[i][0]+acc[i][1]+acc[i][2]+acc[i][3];
        #pragma unroll
        for (int m=16;m>0;m>>=1) rs += __shfl_xor(rs, m, 64);
        float mu = rs * (1.f/128.f);
        float d0 = acc[i][0]-mu, d1 = acc[i][1]-mu, d2 = acc[i][2]-mu, d3 = acc[i][3]-mu;
        float sq = d0*d0+d1*d1+d2*d2+d3*d3;
        #pragma unroll
        for (int m=16;m>0;m>>=1) sq += __shfl_xor(sq, m, 64);
        float rstd = rsqrtf(sq * (1.f/128.f) + 1e-5f);
        int lidx = l0t + i;
        os[(c0+0)*18 + lidx] = d0*rstd*gm.x + bt.x;
        os[(c0+1)*18 + lidx] = d1*rstd*gm.y + bt.y;
        os[(c0+2)*18 + lidx] = d2*rstd*gm.z + bt.z;
        os[(c0+3)*18 + lidx] = d3*rstd*gm.w + bt.w;
    }
    __syncthreads();
    // store: cc = t>>1 (0..127), sel = t&1 -> 8 consecutive l = 32B per lane; full 64B lines per c
    {
        int cc = t >> 1, sel = t & 1;
        const float* ip = &os[cc*18 + sel*8];
        float2 a0 = *(const float2*)(ip);
        float2 a1 = *(const float2*)(ip+2);
        float2 a2 = *(const float2*)(ip+4);
        float2 a3 = *(const float2*)(ip+6);
        float* op = out + ((size_t)(b*OUTC + cc))*Lseq + l0 + sel*8;
        *(float4*)(op)   = make_float4(a0.x,a0.y,a1.x,a1.y);
        *(float4*)(op+4) = make_float4(a2.x,a2.y,a3.x,a3.y);
    }
}

extern "C" void kernel_launch(void* const* d_in, const int* in_sizes, int n_in,
                              void* d_out, int out_size, void* d_ws, size_t ws_size,
                              hipStream_t stream) {
    const float* x1    = (const float*)d_in[0];
    const float* Win   = (const float*)d_in[1];
    const float* convw = (const float*)d_in[2];
    const float* convb = (const float*)d_in[3];
    const float* Wx    = (const float*)d_in[4];
    const float* Wdt   = (const float*)d_in[5];
    const float* bdt   = (const float*)d_in[6];
    const float* Alog  = (const float*)d_in[7];
    const float* Dv    = (const float*)d_in[8];
    const float* Wout  = (const float*)d_in[9];
    const float* lng   = (const float*)d_in[10];
    const float* lnb   = (const float*)d_in[11];
    float* out = (float*)d_out;

    float* ws  = (float*)d_ws;
    float* xin = ws;                        // 2,097,152 floats (dead after conv; reused as Iw)
    float* zs  = xin + 2097152;             // 2,097,152
    float* xc  = zs  + 2097152;             // 2,097,152
    float* dt  = xc  + 2097152;             // 2,097,152
    float* Bm  = dt  + 2097152;             //   131,072
    float* Cm  = Bm  + 131072;              //   131,072
    float2* PSw = (float2*)(Cm + 131072);   // 2,097,152 float2 = 4,194,304 floats (~51.4 MB total)
    float* Iw  = xin;                       // alias: written by scan2, read by scan3out

    k_inproj    <<<512,  256, 0, stream>>>(x1, Win, xin, zs);
    k_conv_scan1<<<256,  256, 0, stream>>>(xin, convw, convb, Wx, Wdt, bdt, Alog,
                                           xc, dt, Bm, Cm, PSw);
    k_scan2     <<<32,   256, 0, stream>>>(PSw, Iw);
    k_scan3out  <<<512,  256, 0, stream>>>(dt, xc, zs, Bm, Cm, Alog, Dv, Iw,
                                           Wout, lng, lnb, out);
}